// Round 7
// baseline (497.639 us; speedup 1.0000x reference)
//
#include <hip/hip_runtime.h>
#include <hip/hip_bf16.h>
#include <stdint.h>

#define HEADS 4
#define SLOPE 0.2f

typedef unsigned short u16;
typedef float f32x4 __attribute__((ext_vector_type(4)));
typedef short s16x8 __attribute__((ext_vector_type(8)));
typedef unsigned short u16x4 __attribute__((ext_vector_type(4)));

__device__ __forceinline__ u16 f2bf(float f) {
    unsigned int u = __float_as_uint(f);
    u = (u + 0x7fffu + ((u >> 16) & 1u)) >> 16;   // round-to-nearest-even
    return (u16)u;
}
__device__ __forceinline__ float bf2f(u16 v) {
    return __uint_as_float(((unsigned int)v) << 16);
}
__device__ __forceinline__ float fin(float x) {
    return (x == x && fabsf(x) < 1e30f) ? x : 0.f;
}

// ---------------------------------------------------------------- fused prep + count
// Section order: [count atomics][cast inp->Xb][W1t][W2t][W3t]. Count dispatches
// first so its 850K latency-bound random atomics overlap the streaming cast /
// transpose waves. deg pre-zeroed via hipMemsetAsync. The atomic's return value
// IS the edge's rank within its destination row (stored coalesced) -> placement
// later runs with zero atomics.  (R6's 8-way sharding REGRESSED; reverted.)
__global__ void prep_kernel(const float* __restrict__ inp, u16* __restrict__ Xb,
                            const float* __restrict__ W1, u16* __restrict__ Wt1,
                            const float* __restrict__ W2, u16* __restrict__ Wt2,
                            const float* __restrict__ W3, u16* __restrict__ Wt3,
                            const int* __restrict__ dst, int* __restrict__ deg,
                            int* __restrict__ rank, int E, int N) {
    int i = blockIdx.x * blockDim.x + threadIdx.x;
    int Etot = E + N;
    if (i < Etot) {                       // count: rank-returning atomic
        int d = (i < E) ? dst[i] : (i - E);   // self-loops appended
        d = ((unsigned)d < (unsigned)N) ? d : 0;
        rank[i] = atomicAdd(&deg[d], 1);
        return;
    }
    i -= Etot;
    int cast4 = N * 32;                   // N*128/4 vec4 groups
    if (i < cast4) {
        f32x4 v = *(const f32x4*)(inp + (size_t)i * 4);
        u16x4 o;
        #pragma unroll
        for (int j = 0; j < 4; j++) o[j] = f2bf(fin(v[j]));
        *(u16x4*)(Xb + (size_t)i * 4) = o;
        return;
    }
    i -= cast4;
    if (i >= 0 && i < 128 * 256) {        // W1 [128 x 256] -> Wt1 [256 x 128]
        int k = i >> 8, m = i & 255;
        Wt1[m * 128 + k] = f2bf(fin(W1[i]));
        return;
    }
    i -= 128 * 256;
    if (i >= 0 && i < 256 * 256) {
        int k = i >> 8, m = i & 255;
        Wt2[m * 256 + k] = f2bf(fin(W2[i]));
        return;
    }
    i -= 256 * 256;
    if (i >= 0 && i < 256 * 256) {
        int k = i >> 8, m = i & 255;
        Wt3[m * 256 + k] = f2bf(fin(W3[i]));
    }
}

// Single-dispatch scan: block b redundantly sums deg[0 .. b*1024), then scans
// its own 1024-element chunk (O(B^2) pre-sum is cheap at B=49).
__global__ __launch_bounds__(256) void scan_kernel(const int* __restrict__ deg,
                                                   int* __restrict__ rowstart, int N) {
    __shared__ int wsum[4];
    __shared__ int sm[256];
    int b = blockIdx.x, tid = threadIdx.x;
    int start = b * 1024;
    int pre = 0;
    for (int i = tid; i < start; i += 256) pre += deg[i];
    #pragma unroll
    for (int off = 1; off <= 32; off <<= 1) pre += __shfl_xor(pre, off);
    if ((tid & 63) == 0) wsum[tid >> 6] = pre;
    __syncthreads();
    int block_pre = wsum[0] + wsum[1] + wsum[2] + wsum[3];

    int base = start + tid * 4;
    int v[4]; int s = 0;
    #pragma unroll
    for (int j = 0; j < 4; j++) { int i = base + j; v[j] = (i < N) ? deg[i] : 0; s += v[j]; }
    sm[tid] = s;
    __syncthreads();
    for (int off = 1; off < 256; off <<= 1) {
        int t = (tid >= off) ? sm[tid - off] : 0;
        __syncthreads();
        sm[tid] += t;
        __syncthreads();
    }
    int run = block_pre + sm[tid] - s;
    #pragma unroll
    for (int j = 0; j < 4; j++) {
        int i = base + j;
        if (i < N) { rowstart[i] = run; run += v[j]; }
    }
    if (b == gridDim.x - 1 && tid == 255) rowstart[N] = block_pre + sm[255];
}

// Atomic-free placement: pos = rowstart[d] + rank[i].
__global__ void place_kernel(const int* __restrict__ src, const int* __restrict__ dst,
                             const int* __restrict__ rowstart, const int* __restrict__ rank,
                             int* __restrict__ csr, int E, int N) {
    int i = blockIdx.x * blockDim.x + threadIdx.x;
    if (i < E + N) {
        int s, d;
        if (i < E) { s = src[i]; d = dst[i]; }
        else       { s = i - E; d = i - E; }
        s = ((unsigned)s < (unsigned)N) ? s : 0;
        d = ((unsigned)d < (unsigned)N) ? d : 0;
        int pos = rowstart[d] + rank[i];
        if ((unsigned)pos < (unsigned)(E + N)) csr[pos] = s;
    }
}

// ---------------------------------------------------------------- GEMM + fused alphas
// LDS-staged MFMA GEMM. Block tile 64 x 256 (full N), BK=64, 4 waves; each wave
// owns a 64x64 column strip = exactly one head. LDS rows padded to 72 elems
// (144 B) so ds_read_b128 fragments land 2-way bank aliasing (free). Staging
// loads are coalesced 128-B row segments; next k-step's loads issue before the
// MFMA block so HBM latency hides under compute.
__global__ __launch_bounds__(256, 3) void gemm_kernel(
        const u16* __restrict__ X, const u16* __restrict__ Wt,
        u16* __restrict__ Hout, const float* __restrict__ att_src,
        const float* __restrict__ att_dst, float* __restrict__ as_out,
        float* __restrict__ ad_out, int N, int K) {
    __shared__ __align__(16) u16 As[64 * 72];    //  9216 B
    __shared__ __align__(16) u16 Bs[256 * 72];   // 36864 B
    int t = threadIdx.x;
    int wv = t >> 6, lane = t & 63;
    int quad = lane >> 4, l16 = lane & 15;
    int m0 = blockIdx.x * 64;
    int n0 = wv * 64;
    int srow = t >> 3, sslot = t & 7;   // staging: row-within-lot, 16B slot

    f32x4 acc[4][4];
    #pragma unroll
    for (int r = 0; r < 4; r++)
        #pragma unroll
        for (int c = 0; c < 4; c++) acc[r][c] = (f32x4){0.f, 0.f, 0.f, 0.f};

    const int nsteps = K >> 6;
    s16x8 ra[2], rb[8];
    {   // prologue: load k-step 0 to regs
        #pragma unroll
        for (int s = 0; s < 2; s++) {
            int rg = m0 + s * 32 + srow; rg = rg < N ? rg : N - 1;
            ra[s] = *(const s16x8*)(X + (size_t)rg * K + sslot * 8);
        }
        #pragma unroll
        for (int s = 0; s < 8; s++) {
            int n = s * 32 + srow;
            rb[s] = *(const s16x8*)(Wt + (size_t)n * K + sslot * 8);
        }
    }
    for (int step = 0; step < nsteps; step++) {
        __syncthreads();
        #pragma unroll
        for (int s = 0; s < 2; s++)
            *(s16x8*)(As + (s * 32 + srow) * 72 + sslot * 8) = ra[s];
        #pragma unroll
        for (int s = 0; s < 8; s++)
            *(s16x8*)(Bs + (s * 32 + srow) * 72 + sslot * 8) = rb[s];
        __syncthreads();
        if (step + 1 < nsteps) {        // prefetch next k-step (overlaps MFMA)
            int k0 = (step + 1) << 6;
            #pragma unroll
            for (int s = 0; s < 2; s++) {
                int rg = m0 + s * 32 + srow; rg = rg < N ? rg : N - 1;
                ra[s] = *(const s16x8*)(X + (size_t)rg * K + k0 + sslot * 8);
            }
            #pragma unroll
            for (int s = 0; s < 8; s++) {
                int n = s * 32 + srow;
                rb[s] = *(const s16x8*)(Wt + (size_t)n * K + k0 + sslot * 8);
            }
        }
        #pragma unroll
        for (int subk = 0; subk < 2; subk++) {
            s16x8 af[4], bfr[4];
            #pragma unroll
            for (int r = 0; r < 4; r++)
                af[r] = *(const s16x8*)(As + (r * 16 + l16) * 72 + subk * 32 + quad * 8);
            #pragma unroll
            for (int c = 0; c < 4; c++)
                bfr[c] = *(const s16x8*)(Bs + (n0 + c * 16 + l16) * 72 + subk * 32 + quad * 8);
            #pragma unroll
            for (int r = 0; r < 4; r++)
                #pragma unroll
                for (int c = 0; c < 4; c++)
                    acc[r][c] = __builtin_amdgcn_mfma_f32_16x16x32_bf16(af[r], bfr[c], acc[r][c], 0, 0, 0);
        }
    }

    // Epilogue: store bf16 H and alpha partials. C/D layout:
    // col = n0 + c*16 + l16, row = m0 + r*16 + quad*4 + j. Wave = head wv.
    float aps[4][4], apd[4][4];   // [r][j]
    #pragma unroll
    for (int r = 0; r < 4; r++)
        #pragma unroll
        for (int j = 0; j < 4; j++) { aps[r][j] = 0.f; apd[r][j] = 0.f; }

    #pragma unroll
    for (int r = 0; r < 4; r++) {
        int rowb = m0 + r * 16 + quad * 4;
        #pragma unroll
        for (int c = 0; c < 4; c++) {
            int col = n0 + c * 16 + l16;
            float av = fin(att_src[col]);
            float dv = fin(att_dst[col]);
            #pragma unroll
            for (int j = 0; j < 4; j++) {
                int row = rowb + j;
                float v = acc[r][c][j];
                aps[r][j] += v * av;
                apd[r][j] += v * dv;
                if (row < N) Hout[(size_t)row * 256 + col] = f2bf(v);
            }
        }
    }
    #pragma unroll
    for (int off = 1; off <= 8; off <<= 1)
        #pragma unroll
        for (int r = 0; r < 4; r++)
            #pragma unroll
            for (int j = 0; j < 4; j++) {
                aps[r][j] += __shfl_xor(aps[r][j], off);
                apd[r][j] += __shfl_xor(apd[r][j], off);
            }
    if (l16 == 0) {
        #pragma unroll
        for (int r = 0; r < 4; r++) {
            int rowb = m0 + r * 16 + quad * 4;
            #pragma unroll
            for (int j = 0; j < 4; j++) {
                int row = rowb + j;
                if (row < N) {
                    as_out[row * 4 + wv] = aps[r][j];
                    ad_out[row * 4 + wv] = apd[r][j];
                }
            }
        }
    }
}

// ---------------------------------------------------------------- fused softmax-gather
// Wave per node; 2 half-wave edge slots; lane covers 8 channels (16 B load) of
// head h = (lane&31)>>3. Inline max-free softmax (clamp 80). Edge loop unrolled
// x4 per slot -> 8 independent row loads in flight per wave.
// DIAGNOSTIC SPLIT: processes nodes [n_begin, n_end) so each layer's gather runs
// as 4 quarter dispatches (~17 us) -> the duration-sorted top-5 profile view
// exposes prep/place/gemm durations instead of being masked by 68-us gathers.
__global__ __launch_bounds__(256) void gather_kernel(
        const u16* __restrict__ Hb, const float* __restrict__ asrc,
        const float* __restrict__ adst, const int* __restrict__ rowstart,
        const int* __restrict__ csr, const float* __restrict__ bias,
        u16* __restrict__ outb, float* __restrict__ outf, int write_f32,
        int n_begin, int n_end, int Etot) {
    int wv = threadIdx.x >> 6, lane = threadIdx.x & 63;
    int n = n_begin + blockIdx.x * 4 + wv;
    if (n >= n_end) return;
    int es = lane >> 5, c = lane & 31;    // edge slot; 8-channel group
    int h = c >> 3;
    int i0 = rowstart[n], i1 = rowstart[n + 1];
    i0 = min(max(i0, 0), Etot);
    i1 = min(max(i1, i0), Etot);

    float adh = adst[n * 4 + h];
    float acc[8];
    float ws = 0.f;
    #pragma unroll
    for (int j = 0; j < 8; j++) acc[j] = 0.f;

    int i = i0 + es;
    for (; i + 6 < i1; i += 8) {          // x4 unroll: 4 independent lines/slot
        int ss[4];
        #pragma unroll
        for (int u = 0; u < 4; u++) {
            int s = csr[i + 2 * u];
            ss[u] = ((unsigned)s < (unsigned)Etot) ? s : 0;
        }
        float e[4]; s16x8 hv[4];
        #pragma unroll
        for (int u = 0; u < 4; u++) {
            e[u] = asrc[ss[u] * 4 + h] + adh;
            hv[u] = *(const s16x8*)(Hb + (size_t)ss[u] * 256 + c * 8);
        }
        #pragma unroll
        for (int u = 0; u < 4; u++) {
            float ee = e[u] > 0.f ? e[u] : SLOPE * e[u];
            float w = __expf(fminf(ee, 80.f));
            ws += w;
            #pragma unroll
            for (int j = 0; j < 8; j++) acc[j] += w * bf2f((u16)hv[u][j]);
        }
    }
    for (; i + 2 < i1; i += 4) {
        int sA = csr[i], sB = csr[i + 2];
        sA = ((unsigned)sA < (unsigned)Etot) ? sA : 0;
        sB = ((unsigned)sB < (unsigned)Etot) ? sB : 0;
        float eA = asrc[sA * 4 + h] + adh;
        float eB = asrc[sB * 4 + h] + adh;
        s16x8 hvA = *(const s16x8*)(Hb + (size_t)sA * 256 + c * 8);
        s16x8 hvB = *(const s16x8*)(Hb + (size_t)sB * 256 + c * 8);
        eA = eA > 0.f ? eA : SLOPE * eA;
        eB = eB > 0.f ? eB : SLOPE * eB;
        float wA = __expf(fminf(eA, 80.f));
        float wB = __expf(fminf(eB, 80.f));
        ws += wA + wB;
        #pragma unroll
        for (int j = 0; j < 8; j++)
            acc[j] += wA * bf2f((u16)hvA[j]) + wB * bf2f((u16)hvB[j]);
    }
    if (i < i1) {
        int s = csr[i];
        s = ((unsigned)s < (unsigned)Etot) ? s : 0;
        float e = asrc[s * 4 + h] + adh;
        s16x8 hv = *(const s16x8*)(Hb + (size_t)s * 256 + c * 8);
        e = e > 0.f ? e : SLOPE * e;
        float w = __expf(fminf(e, 80.f));
        ws += w;
        #pragma unroll
        for (int j = 0; j < 8; j++) acc[j] += w * bf2f((u16)hv[j]);
    }

    ws += __shfl_xor(ws, 32);
    #pragma unroll
    for (int j = 0; j < 8; j++) acc[j] += __shfl_xor(acc[j], 32);

    if (es == 0) {
        float invh = (ws > 0.f) ? 1.f / ws : 0.f;
        f32x4 blo = *(const f32x4*)(bias + c * 8);
        f32x4 bhi = *(const f32x4*)(bias + c * 8 + 4);
        size_t base = (size_t)n * 256 + c * 8;
        float o[8];
        #pragma unroll
        for (int j = 0; j < 8; j++) {
            float v = acc[j] * invh + fin(j < 4 ? blo[j] : bhi[j - 4]);
            o[j] = v > 0.f ? v : (__expf(v) - 1.f);   // ELU
        }
        if (write_f32) {
            f32x4 lo = {o[0], o[1], o[2], o[3]}, hi = {o[4], o[5], o[6], o[7]};
            *(f32x4*)(outf + base) = lo;
            *(f32x4*)(outf + base + 4) = hi;
        } else {
            s16x8 ob;
            #pragma unroll
            for (int j = 0; j < 8; j++) ob[j] = (short)f2bf(o[j]);
            *(s16x8*)(outb + base) = ob;
        }
    }
}

// ---------------------------------------------------------------- launch
extern "C" void kernel_launch(void* const* d_in, const int* in_sizes, int n_in,
                              void* d_out, int out_size, void* d_ws, size_t ws_size,
                              hipStream_t stream) {
    const float* inp  = (const float*)d_in[0];
    const int*   ei   = (const int*)d_in[1];
    const float* W1   = (const float*)d_in[2];
    const float* at_s1= (const float*)d_in[3];
    const float* at_d1= (const float*)d_in[4];
    const float* b1   = (const float*)d_in[5];
    const float* W2   = (const float*)d_in[6];
    const float* at_s2= (const float*)d_in[7];
    const float* at_d2= (const float*)d_in[8];
    const float* b2   = (const float*)d_in[9];
    const float* W3   = (const float*)d_in[10];
    const float* at_s3= (const float*)d_in[11];
    const float* at_d3= (const float*)d_in[12];
    const float* b3   = (const float*)d_in[13];

    const int N = in_sizes[0] / 128;   // 50000
    const int E = in_sizes[1] / 2;     // 800000
    const int Etot = E + N;
    const int* esrc = ei;
    const int* edst = ei + E;

    char* p = (char*)d_ws;
    auto alloc = [&](size_t b) -> void* {
        void* q = (void*)p;
        p += (b + 255) & ~(size_t)255;
        return q;
    };
    u16*   Xb       = (u16*)alloc((size_t)N * 256 * 2);
    u16*   Hb       = (u16*)alloc((size_t)N * 256 * 2);
    u16*   Wt1      = (u16*)alloc((size_t)128 * 256 * 2);
    u16*   Wt2      = (u16*)alloc((size_t)256 * 256 * 2);
    u16*   Wt3      = (u16*)alloc((size_t)256 * 256 * 2);
    float* asb      = (float*)alloc((size_t)N * 4 * 4);
    float* adb      = (float*)alloc((size_t)N * 4 * 4);
    int*   deg      = (int*)alloc((size_t)N * 4);
    int*   rowstart = (int*)alloc((size_t)(N + 1) * 4);
    int*   rank     = (int*)alloc((size_t)Etot * 4);
    int*   csr      = (int*)alloc((size_t)Etot * 4);
    float* outf     = (float*)d_out;

    const int SB = (N + 1023) / 1024;
    const int prep_total = Etot + N * 32 + 128 * 256 + 2 * 256 * 256;

    hipMemsetAsync(deg, 0, (size_t)N * 4, stream);
    prep_kernel<<<(prep_total + 255) / 256, 256, 0, stream>>>(
        inp, Xb, W1, Wt1, W2, Wt2, W3, Wt3, edst, deg, rank, E, N);
    scan_kernel<<<SB, 256, 0, stream>>>(deg, rowstart, N);
    place_kernel<<<(Etot + 255) / 256, 256, 0, stream>>>(esrc, edst, rowstart, rank, csr, E, N);

    const int gemm_grid = (N + 63) / 64;
    const int NQ = (N + 3) / 4;            // nodes per gather quarter
    const int qgrid = (NQ + 3) / 4;

    auto gather4 = [&](const float* bias, u16* ob, float* of, int wf) {
        for (int q = 0; q < 4; q++) {
            int nb = q * NQ;
            int ne = min(nb + NQ, N);
            gather_kernel<<<qgrid, 256, 0, stream>>>(Hb, asb, adb, rowstart, csr,
                                                     bias, ob, of, wf, nb, ne, Etot);
        }
    };

    // layer 1 (K=128)
    gemm_kernel<<<gemm_grid, 256, 0, stream>>>(Xb, Wt1, Hb, at_s1, at_d1, asb, adb, N, 128);
    gather4(b1, Xb, outf, 0);
    // layer 2 (K=256)
    gemm_kernel<<<gemm_grid, 256, 0, stream>>>(Xb, Wt2, Hb, at_s2, at_d2, asb, adb, N, 256);
    gather4(b2, Xb, outf, 0);
    // layer 3 (K=256) -> fp32 d_out
    gemm_kernel<<<gemm_grid, 256, 0, stream>>>(Xb, Wt3, Hb, at_s3, at_d3, asb, adb, N, 256);
    gather4(b3, Xb, outf, 1);
}

// Round 8
// 463.727 us; speedup vs baseline: 1.0731x; 1.0731x over previous
//
#include <hip/hip_runtime.h>
#include <hip/hip_bf16.h>
#include <stdint.h>

#define HEADS 4
#define SLOPE 0.2f
#define DEGS 16   // deg stride: one counter per 64-B line (kills same-line atomic serialization)

typedef unsigned short u16;
typedef float f32x4 __attribute__((ext_vector_type(4)));
typedef short s16x8 __attribute__((ext_vector_type(8)));
typedef unsigned short u16x4 __attribute__((ext_vector_type(4)));

__device__ __forceinline__ u16 f2bf(float f) {
    unsigned int u = __float_as_uint(f);
    u = (u + 0x7fffu + ((u >> 16) & 1u)) >> 16;   // round-to-nearest-even
    return (u16)u;
}
__device__ __forceinline__ float bf2f(u16 v) {
    return __uint_as_float(((unsigned int)v) << 16);
}
__device__ __forceinline__ float fin(float x) {
    return (x == x && fabsf(x) < 1e30f) ? x : 0.f;
}

// ---------------------------------------------------------------- fused prep + count
// Block-section mapping: [count atomics][cast inp->Xb][LDS-tiled W transposes].
// R7 profile showed prep=44us, VALU 2.5%, WRITE 43.5MB (27MB = transpose write
// amplification: 2-B stores at 256/512-B stride dirty full 64-B sectors).
// Fixes: (a) 64x64 LDS tile transpose -> coalesced reads AND writes;
// (b) deg padded to 1 counter/64-B line -> same-line atomic chains 272 -> 17.
// deg pre-zeroed via hipMemsetAsync (N*DEGS ints).
__global__ void prep_kernel(const float* __restrict__ inp, u16* __restrict__ Xb,
                            const float* __restrict__ W1, u16* __restrict__ Wt1,
                            const float* __restrict__ W2, u16* __restrict__ Wt2,
                            const float* __restrict__ W3, u16* __restrict__ Wt3,
                            const int* __restrict__ dst, int* __restrict__ deg,
                            int* __restrict__ rank, int E, int N) {
    __shared__ u16 tile[64][68];          // 68 pad: 8-B aligned rows, conflict-free
    int Etot = E + N;
    int CB = (Etot + 255) >> 8;
    int XB = (N * 32 + 255) >> 8;
    int b = blockIdx.x;
    if (b < CB) {                          // --- count: rank-returning atomic
        int i = b * 256 + threadIdx.x;
        if (i < Etot) {
            int d = (i < E) ? dst[i] : (i - E);   // self-loops appended
            d = ((unsigned)d < (unsigned)N) ? d : 0;
            rank[i] = atomicAdd(&deg[d * DEGS], 1);
        }
        return;
    }
    b -= CB;
    if (b < XB) {                          // --- cast inp -> Xb (vec4)
        int i = b * 256 + threadIdx.x;
        if (i < N * 32) {
            f32x4 v = *(const f32x4*)(inp + (size_t)i * 4);
            u16x4 o;
            #pragma unroll
            for (int j = 0; j < 4; j++) o[j] = f2bf(fin(v[j]));
            *(u16x4*)(Xb + (size_t)i * 4) = o;
        }
        return;
    }
    b -= XB;                               // --- transposes: 40 blocks of 64x64 tiles
    const float* W; u16* Wt; int K, kt, mt;
    if (b < 8)       { W = W1; Wt = Wt1; K = 128; kt = b >> 2; mt = b & 3; }
    else if (b < 24) { b -= 8;  W = W2; Wt = Wt2; K = 256; kt = b >> 2; mt = b & 3; }
    else             { b -= 24; W = W3; Wt = Wt3; K = 256; kt = b >> 2; mt = b & 3; }
    int k0 = kt * 64, m0 = mt * 64;
    int t = threadIdx.x;
    int rr = t >> 4, cc = (t & 15) * 4;
    #pragma unroll
    for (int j = 0; j < 4; j++) {
        int row = rr + 16 * j;                      // k-index
        f32x4 v = *(const f32x4*)(W + (size_t)(k0 + row) * 256 + m0 + cc);
        #pragma unroll
        for (int q = 0; q < 4; q++) tile[row][cc + q] = f2bf(fin(v[q]));
    }
    __syncthreads();
    #pragma unroll
    for (int j = 0; j < 4; j++) {
        int orow = rr + 16 * j;                     // m-index
        u16x4 o;
        #pragma unroll
        for (int q = 0; q < 4; q++) o[q] = tile[cc + q][orow];
        *(u16x4*)(Wt + (size_t)(m0 + orow) * K + k0 + cc) = o;   // coalesced
    }
}

// Single-dispatch scan: block b redundantly sums deg[0 .. b*1024), then scans
// its own 1024-element chunk (O(B^2) pre-sum is cheap at B=49). deg is strided.
__global__ __launch_bounds__(256) void scan_kernel(const int* __restrict__ deg,
                                                   int* __restrict__ rowstart, int N) {
    __shared__ int wsum[4];
    __shared__ int sm[256];
    int b = blockIdx.x, tid = threadIdx.x;
    int start = b * 1024;
    int pre = 0;
    for (int i = tid; i < start; i += 256) pre += deg[i * DEGS];
    #pragma unroll
    for (int off = 1; off <= 32; off <<= 1) pre += __shfl_xor(pre, off);
    if ((tid & 63) == 0) wsum[tid >> 6] = pre;
    __syncthreads();
    int block_pre = wsum[0] + wsum[1] + wsum[2] + wsum[3];

    int base = start + tid * 4;
    int v[4]; int s = 0;
    #pragma unroll
    for (int j = 0; j < 4; j++) {
        int i = base + j;
        v[j] = (i < N) ? deg[i * DEGS] : 0;
        s += v[j];
    }
    sm[tid] = s;
    __syncthreads();
    for (int off = 1; off < 256; off <<= 1) {
        int t = (tid >= off) ? sm[tid - off] : 0;
        __syncthreads();
        sm[tid] += t;
        __syncthreads();
    }
    int run = block_pre + sm[tid] - s;
    #pragma unroll
    for (int j = 0; j < 4; j++) {
        int i = base + j;
        if (i < N) { rowstart[i] = run; run += v[j]; }
    }
    if (b == gridDim.x - 1 && tid == 255) rowstart[N] = block_pre + sm[255];
}

// Atomic-free placement: pos = rowstart[d] + rank[i]. NT scattered store.
__global__ void place_kernel(const int* __restrict__ src, const int* __restrict__ dst,
                             const int* __restrict__ rowstart, const int* __restrict__ rank,
                             int* __restrict__ csr, int E, int N) {
    int i = blockIdx.x * blockDim.x + threadIdx.x;
    if (i < E + N) {
        int s, d;
        if (i < E) { s = src[i]; d = dst[i]; }
        else       { s = i - E; d = i - E; }
        s = ((unsigned)s < (unsigned)N) ? s : 0;
        d = ((unsigned)d < (unsigned)N) ? d : 0;
        int pos = rowstart[d] + rank[i];
        if ((unsigned)pos < (unsigned)(E + N))
            __builtin_nontemporal_store(s, csr + pos);
    }
}

// ---------------------------------------------------------------- GEMM + fused alphas
// LDS-staged MFMA GEMM. Block tile 64 x 256 (full N), BK=64, 4 waves; each wave
// owns a 64x64 column strip = exactly one head. LDS rows padded to 72 elems
// (144 B) so ds_read_b128 fragments land 2-way bank aliasing (free). Staging
// loads are coalesced 128-B row segments; next k-step's loads issue before the
// MFMA block so HBM latency hides under compute.
__global__ __launch_bounds__(256, 3) void gemm_kernel(
        const u16* __restrict__ X, const u16* __restrict__ Wt,
        u16* __restrict__ Hout, const float* __restrict__ att_src,
        const float* __restrict__ att_dst, float* __restrict__ as_out,
        float* __restrict__ ad_out, int N, int K) {
    __shared__ __align__(16) u16 As[64 * 72];    //  9216 B
    __shared__ __align__(16) u16 Bs[256 * 72];   // 36864 B
    int t = threadIdx.x;
    int wv = t >> 6, lane = t & 63;
    int quad = lane >> 4, l16 = lane & 15;
    int m0 = blockIdx.x * 64;
    int n0 = wv * 64;
    int srow = t >> 3, sslot = t & 7;   // staging: row-within-lot, 16B slot

    f32x4 acc[4][4];
    #pragma unroll
    for (int r = 0; r < 4; r++)
        #pragma unroll
        for (int c = 0; c < 4; c++) acc[r][c] = (f32x4){0.f, 0.f, 0.f, 0.f};

    const int nsteps = K >> 6;
    s16x8 ra[2], rb[8];
    {   // prologue: load k-step 0 to regs
        #pragma unroll
        for (int s = 0; s < 2; s++) {
            int rg = m0 + s * 32 + srow; rg = rg < N ? rg : N - 1;
            ra[s] = *(const s16x8*)(X + (size_t)rg * K + sslot * 8);
        }
        #pragma unroll
        for (int s = 0; s < 8; s++) {
            int n = s * 32 + srow;
            rb[s] = *(const s16x8*)(Wt + (size_t)n * K + sslot * 8);
        }
    }
    for (int step = 0; step < nsteps; step++) {
        __syncthreads();
        #pragma unroll
        for (int s = 0; s < 2; s++)
            *(s16x8*)(As + (s * 32 + srow) * 72 + sslot * 8) = ra[s];
        #pragma unroll
        for (int s = 0; s < 8; s++)
            *(s16x8*)(Bs + (s * 32 + srow) * 72 + sslot * 8) = rb[s];
        __syncthreads();
        if (step + 1 < nsteps) {        // prefetch next k-step (overlaps MFMA)
            int k0 = (step + 1) << 6;
            #pragma unroll
            for (int s = 0; s < 2; s++) {
                int rg = m0 + s * 32 + srow; rg = rg < N ? rg : N - 1;
                ra[s] = *(const s16x8*)(X + (size_t)rg * K + k0 + sslot * 8);
            }
            #pragma unroll
            for (int s = 0; s < 8; s++) {
                int n = s * 32 + srow;
                rb[s] = *(const s16x8*)(Wt + (size_t)n * K + k0 + sslot * 8);
            }
        }
        #pragma unroll
        for (int subk = 0; subk < 2; subk++) {
            s16x8 af[4], bfr[4];
            #pragma unroll
            for (int r = 0; r < 4; r++)
                af[r] = *(const s16x8*)(As + (r * 16 + l16) * 72 + subk * 32 + quad * 8);
            #pragma unroll
            for (int c = 0; c < 4; c++)
                bfr[c] = *(const s16x8*)(Bs + (n0 + c * 16 + l16) * 72 + subk * 32 + quad * 8);
            #pragma unroll
            for (int r = 0; r < 4; r++)
                #pragma unroll
                for (int c = 0; c < 4; c++)
                    acc[r][c] = __builtin_amdgcn_mfma_f32_16x16x32_bf16(af[r], bfr[c], acc[r][c], 0, 0, 0);
        }
    }

    // Epilogue: store bf16 H and alpha partials. C/D layout:
    // col = n0 + c*16 + l16, row = m0 + r*16 + quad*4 + j. Wave = head wv.
    float aps[4][4], apd[4][4];   // [r][j]
    #pragma unroll
    for (int r = 0; r < 4; r++)
        #pragma unroll
        for (int j = 0; j < 4; j++) { aps[r][j] = 0.f; apd[r][j] = 0.f; }

    #pragma unroll
    for (int r = 0; r < 4; r++) {
        int rowb = m0 + r * 16 + quad * 4;
        #pragma unroll
        for (int c = 0; c < 4; c++) {
            int col = n0 + c * 16 + l16;
            float av = fin(att_src[col]);
            float dv = fin(att_dst[col]);
            #pragma unroll
            for (int j = 0; j < 4; j++) {
                int row = rowb + j;
                float v = acc[r][c][j];
                aps[r][j] += v * av;
                apd[r][j] += v * dv;
                if (row < N) Hout[(size_t)row * 256 + col] = f2bf(v);
            }
        }
    }
    #pragma unroll
    for (int off = 1; off <= 8; off <<= 1)
        #pragma unroll
        for (int r = 0; r < 4; r++)
            #pragma unroll
            for (int j = 0; j < 4; j++) {
                aps[r][j] += __shfl_xor(aps[r][j], off);
                apd[r][j] += __shfl_xor(apd[r][j], off);
            }
    if (l16 == 0) {
        #pragma unroll
        for (int r = 0; r < 4; r++) {
            int rowb = m0 + r * 16 + quad * 4;
            #pragma unroll
            for (int j = 0; j < 4; j++) {
                int row = rowb + j;
                if (row < N) {
                    as_out[row * 4 + wv] = aps[r][j];
                    ad_out[row * 4 + wv] = apd[r][j];
                }
            }
        }
    }
}

// ---------------------------------------------------------------- fused softmax-gather
// Wave per node; 2 half-wave edge slots; lane covers 8 channels (16 B load) of
// head h = (lane&31)>>3. Inline max-free softmax (clamp 80). Edge loop unrolled
// x4 per slot -> 8 independent row loads in flight per wave.
__global__ __launch_bounds__(256) void gather_kernel(
        const u16* __restrict__ Hb, const float* __restrict__ asrc,
        const float* __restrict__ adst, const int* __restrict__ rowstart,
        const int* __restrict__ csr, const float* __restrict__ bias,
        u16* __restrict__ outb, float* __restrict__ outf, int write_f32,
        int N, int Etot) {
    int wv = threadIdx.x >> 6, lane = threadIdx.x & 63;
    int n = blockIdx.x * 4 + wv;
    if (n >= N) return;
    int es = lane >> 5, c = lane & 31;    // edge slot; 8-channel group
    int h = c >> 3;
    int i0 = rowstart[n], i1 = rowstart[n + 1];
    i0 = min(max(i0, 0), Etot);
    i1 = min(max(i1, i0), Etot);

    float adh = adst[n * 4 + h];
    float acc[8];
    float ws = 0.f;
    #pragma unroll
    for (int j = 0; j < 8; j++) acc[j] = 0.f;

    int i = i0 + es;
    for (; i + 6 < i1; i += 8) {          // x4 unroll: 4 independent lines/slot
        int ss[4];
        #pragma unroll
        for (int u = 0; u < 4; u++) {
            int s = csr[i + 2 * u];
            ss[u] = ((unsigned)s < (unsigned)N) ? s : 0;
        }
        float e[4]; s16x8 hv[4];
        #pragma unroll
        for (int u = 0; u < 4; u++) {
            e[u] = asrc[ss[u] * 4 + h] + adh;
            hv[u] = *(const s16x8*)(Hb + (size_t)ss[u] * 256 + c * 8);
        }
        #pragma unroll
        for (int u = 0; u < 4; u++) {
            float ee = e[u] > 0.f ? e[u] : SLOPE * e[u];
            float w = __expf(fminf(ee, 80.f));
            ws += w;
            #pragma unroll
            for (int j = 0; j < 8; j++) acc[j] += w * bf2f((u16)hv[u][j]);
        }
    }
    for (; i + 2 < i1; i += 4) {
        int sA = csr[i], sB = csr[i + 2];
        sA = ((unsigned)sA < (unsigned)N) ? sA : 0;
        sB = ((unsigned)sB < (unsigned)N) ? sB : 0;
        float eA = asrc[sA * 4 + h] + adh;
        float eB = asrc[sB * 4 + h] + adh;
        s16x8 hvA = *(const s16x8*)(Hb + (size_t)sA * 256 + c * 8);
        s16x8 hvB = *(const s16x8*)(Hb + (size_t)sB * 256 + c * 8);
        eA = eA > 0.f ? eA : SLOPE * eA;
        eB = eB > 0.f ? eB : SLOPE * eB;
        float wA = __expf(fminf(eA, 80.f));
        float wB = __expf(fminf(eB, 80.f));
        ws += wA + wB;
        #pragma unroll
        for (int j = 0; j < 8; j++)
            acc[j] += wA * bf2f((u16)hvA[j]) + wB * bf2f((u16)hvB[j]);
    }
    if (i < i1) {
        int s = csr[i];
        s = ((unsigned)s < (unsigned)N) ? s : 0;
        float e = asrc[s * 4 + h] + adh;
        s16x8 hv = *(const s16x8*)(Hb + (size_t)s * 256 + c * 8);
        e = e > 0.f ? e : SLOPE * e;
        float w = __expf(fminf(e, 80.f));
        ws += w;
        #pragma unroll
        for (int j = 0; j < 8; j++) acc[j] += w * bf2f((u16)hv[j]);
    }

    ws += __shfl_xor(ws, 32);
    #pragma unroll
    for (int j = 0; j < 8; j++) acc[j] += __shfl_xor(acc[j], 32);

    if (es == 0) {
        float invh = (ws > 0.f) ? 1.f / ws : 0.f;
        f32x4 blo = *(const f32x4*)(bias + c * 8);
        f32x4 bhi = *(const f32x4*)(bias + c * 8 + 4);
        size_t base = (size_t)n * 256 + c * 8;
        float o[8];
        #pragma unroll
        for (int j = 0; j < 8; j++) {
            float v = acc[j] * invh + fin(j < 4 ? blo[j] : bhi[j - 4]);
            o[j] = v > 0.f ? v : (__expf(v) - 1.f);   // ELU
        }
        if (write_f32) {
            f32x4 lo = {o[0], o[1], o[2], o[3]}, hi = {o[4], o[5], o[6], o[7]};
            *(f32x4*)(outf + base) = lo;
            *(f32x4*)(outf + base + 4) = hi;
        } else {
            s16x8 ob;
            #pragma unroll
            for (int j = 0; j < 8; j++) ob[j] = (short)f2bf(o[j]);
            *(s16x8*)(outb + base) = ob;
        }
    }
}

// ---------------------------------------------------------------- launch
extern "C" void kernel_launch(void* const* d_in, const int* in_sizes, int n_in,
                              void* d_out, int out_size, void* d_ws, size_t ws_size,
                              hipStream_t stream) {
    const float* inp  = (const float*)d_in[0];
    const int*   ei   = (const int*)d_in[1];
    const float* W1   = (const float*)d_in[2];
    const float* at_s1= (const float*)d_in[3];
    const float* at_d1= (const float*)d_in[4];
    const float* b1   = (const float*)d_in[5];
    const float* W2   = (const float*)d_in[6];
    const float* at_s2= (const float*)d_in[7];
    const float* at_d2= (const float*)d_in[8];
    const float* b2   = (const float*)d_in[9];
    const float* W3   = (const float*)d_in[10];
    const float* at_s3= (const float*)d_in[11];
    const float* at_d3= (const float*)d_in[12];
    const float* b3   = (const float*)d_in[13];

    const int N = in_sizes[0] / 128;   // 50000
    const int E = in_sizes[1] / 2;     // 800000
    const int Etot = E + N;
    const int* esrc = ei;
    const int* edst = ei + E;

    char* p = (char*)d_ws;
    auto alloc = [&](size_t b) -> void* {
        void* q = (void*)p;
        p += (b + 255) & ~(size_t)255;
        return q;
    };
    u16*   Xb       = (u16*)alloc((size_t)N * 256 * 2);
    u16*   Hb       = (u16*)alloc((size_t)N * 256 * 2);
    u16*   Wt1      = (u16*)alloc((size_t)128 * 256 * 2);
    u16*   Wt2      = (u16*)alloc((size_t)256 * 256 * 2);
    u16*   Wt3      = (u16*)alloc((size_t)256 * 256 * 2);
    float* asb      = (float*)alloc((size_t)N * 4 * 4);
    float* adb      = (float*)alloc((size_t)N * 4 * 4);
    int*   deg      = (int*)alloc((size_t)N * DEGS * 4);
    int*   rowstart = (int*)alloc((size_t)(N + 1) * 4);
    int*   rank     = (int*)alloc((size_t)Etot * 4);
    int*   csr      = (int*)alloc((size_t)Etot * 4);
    float* outf     = (float*)d_out;

    const int SB = (N + 1023) / 1024;
    const int CB = (Etot + 255) >> 8;
    const int XB = (N * 32 + 255) >> 8;
    const int prep_blocks = CB + XB + 40;

    hipMemsetAsync(deg, 0, (size_t)N * DEGS * 4, stream);
    prep_kernel<<<prep_blocks, 256, 0, stream>>>(
        inp, Xb, W1, Wt1, W2, Wt2, W3, Wt3, edst, deg, rank, E, N);
    scan_kernel<<<SB, 256, 0, stream>>>(deg, rowstart, N);
    place_kernel<<<(Etot + 255) / 256, 256, 0, stream>>>(esrc, edst, rowstart, rank, csr, E, N);

    const int gemm_grid = (N + 63) / 64;
    const int node_grid = (N + 3) / 4;

    // layer 1 (K=128)
    gemm_kernel<<<gemm_grid, 256, 0, stream>>>(Xb, Wt1, Hb, at_s1, at_d1, asb, adb, N, 128);
    gather_kernel<<<node_grid, 256, 0, stream>>>(Hb, asb, adb, rowstart, csr, b1,
                                                 Xb, outf, 0, N, Etot);
    // layer 2 (K=256)
    gemm_kernel<<<gemm_grid, 256, 0, stream>>>(Xb, Wt2, Hb, at_s2, at_d2, asb, adb, N, 256);
    gather_kernel<<<node_grid, 256, 0, stream>>>(Hb, asb, adb, rowstart, csr, b2,
                                                 Xb, outf, 0, N, Etot);
    // layer 3 (K=256) -> fp32 d_out
    gemm_kernel<<<gemm_grid, 256, 0, stream>>>(Xb, Wt3, Hb, at_s3, at_d3, asb, adb, N, 256);
    gather_kernel<<<node_grid, 256, 0, stream>>>(Hb, asb, adb, rowstart, csr, b3,
                                                 Xb, outf, 1, N, Etot);
}

// Round 9
// 443.269 us; speedup vs baseline: 1.1227x; 1.0462x over previous
//
#include <hip/hip_runtime.h>
#include <hip/hip_bf16.h>
#include <stdint.h>

#define HEADS 4
#define SLOPE 0.2f

typedef unsigned short u16;
typedef float f32x4 __attribute__((ext_vector_type(4)));
typedef short s16x8 __attribute__((ext_vector_type(8)));
typedef unsigned short u16x4 __attribute__((ext_vector_type(4)));

__device__ __forceinline__ u16 f2bf(float f) {
    unsigned int u = __float_as_uint(f);
    u = (u + 0x7fffu + ((u >> 16) & 1u)) >> 16;   // round-to-nearest-even
    return (u16)u;
}
__device__ __forceinline__ float bf2f(u16 v) {
    return __uint_as_float(((unsigned int)v) << 16);
}
__device__ __forceinline__ float fin(float x) {
    return (x == x && fabsf(x) < 1e30f) ? x : 0.f;
}

// ---------------------------------------------------------------- fused prep + count
// Block-section mapping: [count atomics][cast inp->Xb][LDS-tiled W transposes].
// R7 profile: prep=44us, VALU 2.5%, WRITE 43.5MB of which ~27MB was transpose
// write amplification (2-B stores at 256/512-B lane stride dirty 64-B sectors).
// Fix (ONLY change vs R5): 64x64 LDS-tile transpose -> coalesced reads+writes.
// deg stays DENSE (R8's DEGS padding + NT place store regressed; reverted).
__global__ void prep_kernel(const float* __restrict__ inp, u16* __restrict__ Xb,
                            const float* __restrict__ W1, u16* __restrict__ Wt1,
                            const float* __restrict__ W2, u16* __restrict__ Wt2,
                            const float* __restrict__ W3, u16* __restrict__ Wt3,
                            const int* __restrict__ dst, int* __restrict__ deg,
                            int* __restrict__ rank, int E, int N) {
    __shared__ u16 tile[64][68];          // 68 pad: conflict-light column reads
    int Etot = E + N;
    int CB = (Etot + 255) >> 8;
    int XB = (N * 32 + 255) >> 8;
    int b = blockIdx.x;
    if (b < CB) {                          // --- count: rank-returning atomic
        int i = b * 256 + threadIdx.x;
        if (i < Etot) {
            int d = (i < E) ? dst[i] : (i - E);   // self-loops appended
            d = ((unsigned)d < (unsigned)N) ? d : 0;
            rank[i] = atomicAdd(&deg[d], 1);
        }
        return;
    }
    b -= CB;
    if (b < XB) {                          // --- cast inp -> Xb (vec4)
        int i = b * 256 + threadIdx.x;
        if (i < N * 32) {
            f32x4 v = *(const f32x4*)(inp + (size_t)i * 4);
            u16x4 o;
            #pragma unroll
            for (int j = 0; j < 4; j++) o[j] = f2bf(fin(v[j]));
            *(u16x4*)(Xb + (size_t)i * 4) = o;
        }
        return;
    }
    b -= XB;                               // --- transposes: 40 blocks of 64x64 tiles
    const float* W; u16* Wt; int K, kt, mt;
    if (b < 8)       { W = W1; Wt = Wt1; K = 128; kt = b >> 2; mt = b & 3; }
    else if (b < 24) { b -= 8;  W = W2; Wt = Wt2; K = 256; kt = b >> 2; mt = b & 3; }
    else             { b -= 24; W = W3; Wt = Wt3; K = 256; kt = b >> 2; mt = b & 3; }
    int k0 = kt * 64, m0 = mt * 64;
    int t = threadIdx.x;
    int rr = t >> 4, cc = (t & 15) * 4;
    #pragma unroll
    for (int j = 0; j < 4; j++) {
        int row = rr + 16 * j;                      // k-index
        f32x4 v = *(const f32x4*)(W + (size_t)(k0 + row) * 256 + m0 + cc);
        #pragma unroll
        for (int q = 0; q < 4; q++) tile[row][cc + q] = f2bf(fin(v[q]));
    }
    __syncthreads();
    #pragma unroll
    for (int j = 0; j < 4; j++) {
        int orow = rr + 16 * j;                     // m-index
        u16x4 o;
        #pragma unroll
        for (int q = 0; q < 4; q++) o[q] = tile[cc + q][orow];
        *(u16x4*)(Wt + (size_t)(m0 + orow) * K + k0 + cc) = o;   // coalesced
    }
}

// Single-dispatch scan: block b redundantly sums deg[0 .. b*1024), then scans
// its own 1024-element chunk (O(B^2) pre-sum is cheap at B=49).
__global__ __launch_bounds__(256) void scan_kernel(const int* __restrict__ deg,
                                                   int* __restrict__ rowstart, int N) {
    __shared__ int wsum[4];
    __shared__ int sm[256];
    int b = blockIdx.x, tid = threadIdx.x;
    int start = b * 1024;
    int pre = 0;
    for (int i = tid; i < start; i += 256) pre += deg[i];
    #pragma unroll
    for (int off = 1; off <= 32; off <<= 1) pre += __shfl_xor(pre, off);
    if ((tid & 63) == 0) wsum[tid >> 6] = pre;
    __syncthreads();
    int block_pre = wsum[0] + wsum[1] + wsum[2] + wsum[3];

    int base = start + tid * 4;
    int v[4]; int s = 0;
    #pragma unroll
    for (int j = 0; j < 4; j++) { int i = base + j; v[j] = (i < N) ? deg[i] : 0; s += v[j]; }
    sm[tid] = s;
    __syncthreads();
    for (int off = 1; off < 256; off <<= 1) {
        int t = (tid >= off) ? sm[tid - off] : 0;
        __syncthreads();
        sm[tid] += t;
        __syncthreads();
    }
    int run = block_pre + sm[tid] - s;
    #pragma unroll
    for (int j = 0; j < 4; j++) {
        int i = base + j;
        if (i < N) { rowstart[i] = run; run += v[j]; }
    }
    if (b == gridDim.x - 1 && tid == 255) rowstart[N] = block_pre + sm[255];
}

// Atomic-free placement: pos = rowstart[d] + rank[i]. Plain store (NT regressed).
__global__ void place_kernel(const int* __restrict__ src, const int* __restrict__ dst,
                             const int* __restrict__ rowstart, const int* __restrict__ rank,
                             int* __restrict__ csr, int E, int N) {
    int i = blockIdx.x * blockDim.x + threadIdx.x;
    if (i < E + N) {
        int s, d;
        if (i < E) { s = src[i]; d = dst[i]; }
        else       { s = i - E; d = i - E; }
        s = ((unsigned)s < (unsigned)N) ? s : 0;
        d = ((unsigned)d < (unsigned)N) ? d : 0;
        int pos = rowstart[d] + rank[i];
        if ((unsigned)pos < (unsigned)(E + N)) csr[pos] = s;
    }
}

// ---------------------------------------------------------------- GEMM + fused alphas
// LDS-staged MFMA GEMM. Block tile 64 x 256 (full N), BK=64, 4 waves; each wave
// owns a 64x64 column strip = exactly one head. LDS rows padded to 72 elems
// (144 B) so ds_read_b128 fragments land 2-way bank aliasing (free). Staging
// loads are coalesced 128-B row segments; next k-step's loads issue before the
// MFMA block so HBM latency hides under compute.
__global__ __launch_bounds__(256, 3) void gemm_kernel(
        const u16* __restrict__ X, const u16* __restrict__ Wt,
        u16* __restrict__ Hout, const float* __restrict__ att_src,
        const float* __restrict__ att_dst, float* __restrict__ as_out,
        float* __restrict__ ad_out, int N, int K) {
    __shared__ __align__(16) u16 As[64 * 72];    //  9216 B
    __shared__ __align__(16) u16 Bs[256 * 72];   // 36864 B
    int t = threadIdx.x;
    int wv = t >> 6, lane = t & 63;
    int quad = lane >> 4, l16 = lane & 15;
    int m0 = blockIdx.x * 64;
    int n0 = wv * 64;
    int srow = t >> 3, sslot = t & 7;   // staging: row-within-lot, 16B slot

    f32x4 acc[4][4];
    #pragma unroll
    for (int r = 0; r < 4; r++)
        #pragma unroll
        for (int c = 0; c < 4; c++) acc[r][c] = (f32x4){0.f, 0.f, 0.f, 0.f};

    const int nsteps = K >> 6;
    s16x8 ra[2], rb[8];
    {   // prologue: load k-step 0 to regs
        #pragma unroll
        for (int s = 0; s < 2; s++) {
            int rg = m0 + s * 32 + srow; rg = rg < N ? rg : N - 1;
            ra[s] = *(const s16x8*)(X + (size_t)rg * K + sslot * 8);
        }
        #pragma unroll
        for (int s = 0; s < 8; s++) {
            int n = s * 32 + srow;
            rb[s] = *(const s16x8*)(Wt + (size_t)n * K + sslot * 8);
        }
    }
    for (int step = 0; step < nsteps; step++) {
        __syncthreads();
        #pragma unroll
        for (int s = 0; s < 2; s++)
            *(s16x8*)(As + (s * 32 + srow) * 72 + sslot * 8) = ra[s];
        #pragma unroll
        for (int s = 0; s < 8; s++)
            *(s16x8*)(Bs + (s * 32 + srow) * 72 + sslot * 8) = rb[s];
        __syncthreads();
        if (step + 1 < nsteps) {        // prefetch next k-step (overlaps MFMA)
            int k0 = (step + 1) << 6;
            #pragma unroll
            for (int s = 0; s < 2; s++) {
                int rg = m0 + s * 32 + srow; rg = rg < N ? rg : N - 1;
                ra[s] = *(const s16x8*)(X + (size_t)rg * K + k0 + sslot * 8);
            }
            #pragma unroll
            for (int s = 0; s < 8; s++) {
                int n = s * 32 + srow;
                rb[s] = *(const s16x8*)(Wt + (size_t)n * K + k0 + sslot * 8);
            }
        }
        #pragma unroll
        for (int subk = 0; subk < 2; subk++) {
            s16x8 af[4], bfr[4];
            #pragma unroll
            for (int r = 0; r < 4; r++)
                af[r] = *(const s16x8*)(As + (r * 16 + l16) * 72 + subk * 32 + quad * 8);
            #pragma unroll
            for (int c = 0; c < 4; c++)
                bfr[c] = *(const s16x8*)(Bs + (n0 + c * 16 + l16) * 72 + subk * 32 + quad * 8);
            #pragma unroll
            for (int r = 0; r < 4; r++)
                #pragma unroll
                for (int c = 0; c < 4; c++)
                    acc[r][c] = __builtin_amdgcn_mfma_f32_16x16x32_bf16(af[r], bfr[c], acc[r][c], 0, 0, 0);
        }
    }

    // Epilogue: store bf16 H and alpha partials. C/D layout:
    // col = n0 + c*16 + l16, row = m0 + r*16 + quad*4 + j. Wave = head wv.
    float aps[4][4], apd[4][4];   // [r][j]
    #pragma unroll
    for (int r = 0; r < 4; r++)
        #pragma unroll
        for (int j = 0; j < 4; j++) { aps[r][j] = 0.f; apd[r][j] = 0.f; }

    #pragma unroll
    for (int r = 0; r < 4; r++) {
        int rowb = m0 + r * 16 + quad * 4;
        #pragma unroll
        for (int c = 0; c < 4; c++) {
            int col = n0 + c * 16 + l16;
            float av = fin(att_src[col]);
            float dv = fin(att_dst[col]);
            #pragma unroll
            for (int j = 0; j < 4; j++) {
                int row = rowb + j;
                float v = acc[r][c][j];
                aps[r][j] += v * av;
                apd[r][j] += v * dv;
                if (row < N) Hout[(size_t)row * 256 + col] = f2bf(v);
            }
        }
    }
    #pragma unroll
    for (int off = 1; off <= 8; off <<= 1)
        #pragma unroll
        for (int r = 0; r < 4; r++)
            #pragma unroll
            for (int j = 0; j < 4; j++) {
                aps[r][j] += __shfl_xor(aps[r][j], off);
                apd[r][j] += __shfl_xor(apd[r][j], off);
            }
    if (l16 == 0) {
        #pragma unroll
        for (int r = 0; r < 4; r++) {
            int rowb = m0 + r * 16 + quad * 4;
            #pragma unroll
            for (int j = 0; j < 4; j++) {
                int row = rowb + j;
                if (row < N) {
                    as_out[row * 4 + wv] = aps[r][j];
                    ad_out[row * 4 + wv] = apd[r][j];
                }
            }
        }
    }
}

// ---------------------------------------------------------------- fused softmax-gather
// Wave per node; 2 half-wave edge slots; lane covers 8 channels (16 B load) of
// head h = (lane&31)>>3. Inline max-free softmax (clamp 80). Edge loop unrolled
// x4 per slot -> 8 independent row loads in flight per wave.
__global__ __launch_bounds__(256) void gather_kernel(
        const u16* __restrict__ Hb, const float* __restrict__ asrc,
        const float* __restrict__ adst, const int* __restrict__ rowstart,
        const int* __restrict__ csr, const float* __restrict__ bias,
        u16* __restrict__ outb, float* __restrict__ outf, int write_f32,
        int N, int Etot) {
    int wv = threadIdx.x >> 6, lane = threadIdx.x & 63;
    int n = blockIdx.x * 4 + wv;
    if (n >= N) return;
    int es = lane >> 5, c = lane & 31;    // edge slot; 8-channel group
    int h = c >> 3;
    int i0 = rowstart[n], i1 = rowstart[n + 1];
    i0 = min(max(i0, 0), Etot);
    i1 = min(max(i1, i0), Etot);

    float adh = adst[n * 4 + h];
    float acc[8];
    float ws = 0.f;
    #pragma unroll
    for (int j = 0; j < 8; j++) acc[j] = 0.f;

    int i = i0 + es;
    for (; i + 6 < i1; i += 8) {          // x4 unroll: 4 independent lines/slot
        int ss[4];
        #pragma unroll
        for (int u = 0; u < 4; u++) {
            int s = csr[i + 2 * u];
            ss[u] = ((unsigned)s < (unsigned)N) ? s : 0;
        }
        float e[4]; s16x8 hv[4];
        #pragma unroll
        for (int u = 0; u < 4; u++) {
            e[u] = asrc[ss[u] * 4 + h] + adh;
            hv[u] = *(const s16x8*)(Hb + (size_t)ss[u] * 256 + c * 8);
        }
        #pragma unroll
        for (int u = 0; u < 4; u++) {
            float ee = e[u] > 0.f ? e[u] : SLOPE * e[u];
            float w = __expf(fminf(ee, 80.f));
            ws += w;
            #pragma unroll
            for (int j = 0; j < 8; j++) acc[j] += w * bf2f((u16)hv[u][j]);
        }
    }
    for (; i + 2 < i1; i += 4) {
        int sA = csr[i], sB = csr[i + 2];
        sA = ((unsigned)sA < (unsigned)N) ? sA : 0;
        sB = ((unsigned)sB < (unsigned)N) ? sB : 0;
        float eA = asrc[sA * 4 + h] + adh;
        float eB = asrc[sB * 4 + h] + adh;
        s16x8 hvA = *(const s16x8*)(Hb + (size_t)sA * 256 + c * 8);
        s16x8 hvB = *(const s16x8*)(Hb + (size_t)sB * 256 + c * 8);
        eA = eA > 0.f ? eA : SLOPE * eA;
        eB = eB > 0.f ? eB : SLOPE * eB;
        float wA = __expf(fminf(eA, 80.f));
        float wB = __expf(fminf(eB, 80.f));
        ws += wA + wB;
        #pragma unroll
        for (int j = 0; j < 8; j++)
            acc[j] += wA * bf2f((u16)hvA[j]) + wB * bf2f((u16)hvB[j]);
    }
    if (i < i1) {
        int s = csr[i];
        s = ((unsigned)s < (unsigned)N) ? s : 0;
        float e = asrc[s * 4 + h] + adh;
        s16x8 hv = *(const s16x8*)(Hb + (size_t)s * 256 + c * 8);
        e = e > 0.f ? e : SLOPE * e;
        float w = __expf(fminf(e, 80.f));
        ws += w;
        #pragma unroll
        for (int j = 0; j < 8; j++) acc[j] += w * bf2f((u16)hv[j]);
    }

    ws += __shfl_xor(ws, 32);
    #pragma unroll
    for (int j = 0; j < 8; j++) acc[j] += __shfl_xor(acc[j], 32);

    if (es == 0) {
        float invh = (ws > 0.f) ? 1.f / ws : 0.f;
        f32x4 blo = *(const f32x4*)(bias + c * 8);
        f32x4 bhi = *(const f32x4*)(bias + c * 8 + 4);
        size_t base = (size_t)n * 256 + c * 8;
        float o[8];
        #pragma unroll
        for (int j = 0; j < 8; j++) {
            float v = acc[j] * invh + fin(j < 4 ? blo[j] : bhi[j - 4]);
            o[j] = v > 0.f ? v : (__expf(v) - 1.f);   // ELU
        }
        if (write_f32) {
            f32x4 lo = {o[0], o[1], o[2], o[3]}, hi = {o[4], o[5], o[6], o[7]};
            *(f32x4*)(outf + base) = lo;
            *(f32x4*)(outf + base + 4) = hi;
        } else {
            s16x8 ob;
            #pragma unroll
            for (int j = 0; j < 8; j++) ob[j] = (short)f2bf(o[j]);
            *(s16x8*)(outb + base) = ob;
        }
    }
}

// ---------------------------------------------------------------- launch
extern "C" void kernel_launch(void* const* d_in, const int* in_sizes, int n_in,
                              void* d_out, int out_size, void* d_ws, size_t ws_size,
                              hipStream_t stream) {
    const float* inp  = (const float*)d_in[0];
    const int*   ei   = (const int*)d_in[1];
    const float* W1   = (const float*)d_in[2];
    const float* at_s1= (const float*)d_in[3];
    const float* at_d1= (const float*)d_in[4];
    const float* b1   = (const float*)d_in[5];
    const float* W2   = (const float*)d_in[6];
    const float* at_s2= (const float*)d_in[7];
    const float* at_d2= (const float*)d_in[8];
    const float* b2   = (const float*)d_in[9];
    const float* W3   = (const float*)d_in[10];
    const float* at_s3= (const float*)d_in[11];
    const float* at_d3= (const float*)d_in[12];
    const float* b3   = (const float*)d_in[13];

    const int N = in_sizes[0] / 128;   // 50000
    const int E = in_sizes[1] / 2;     // 800000
    const int Etot = E + N;
    const int* esrc = ei;
    const int* edst = ei + E;

    char* p = (char*)d_ws;
    auto alloc = [&](size_t b) -> void* {
        void* q = (void*)p;
        p += (b + 255) & ~(size_t)255;
        return q;
    };
    u16*   Xb       = (u16*)alloc((size_t)N * 256 * 2);
    u16*   Hb       = (u16*)alloc((size_t)N * 256 * 2);
    u16*   Wt1      = (u16*)alloc((size_t)128 * 256 * 2);
    u16*   Wt2      = (u16*)alloc((size_t)256 * 256 * 2);
    u16*   Wt3      = (u16*)alloc((size_t)256 * 256 * 2);
    float* asb      = (float*)alloc((size_t)N * 4 * 4);
    float* adb      = (float*)alloc((size_t)N * 4 * 4);
    int*   deg      = (int*)alloc((size_t)N * 4);
    int*   rowstart = (int*)alloc((size_t)(N + 1) * 4);
    int*   rank     = (int*)alloc((size_t)Etot * 4);
    int*   csr      = (int*)alloc((size_t)Etot * 4);
    float* outf     = (float*)d_out;

    const int SB = (N + 1023) / 1024;
    const int CB = (Etot + 255) >> 8;
    const int XB = (N * 32 + 255) >> 8;
    const int prep_blocks = CB + XB + 40;

    hipMemsetAsync(deg, 0, (size_t)N * 4, stream);
    prep_kernel<<<prep_blocks, 256, 0, stream>>>(
        inp, Xb, W1, Wt1, W2, Wt2, W3, Wt3, edst, deg, rank, E, N);
    scan_kernel<<<SB, 256, 0, stream>>>(deg, rowstart, N);
    place_kernel<<<(Etot + 255) / 256, 256, 0, stream>>>(esrc, edst, rowstart, rank, csr, E, N);

    const int gemm_grid = (N + 63) / 64;
    const int node_grid = (N + 3) / 4;

    // layer 1 (K=128)
    gemm_kernel<<<gemm_grid, 256, 0, stream>>>(Xb, Wt1, Hb, at_s1, at_d1, asb, adb, N, 128);
    gather_kernel<<<node_grid, 256, 0, stream>>>(Hb, asb, adb, rowstart, csr, b1,
                                                 Xb, outf, 0, N, Etot);
    // layer 2 (K=256)
    gemm_kernel<<<gemm_grid, 256, 0, stream>>>(Xb, Wt2, Hb, at_s2, at_d2, asb, adb, N, 256);
    gather_kernel<<<node_grid, 256, 0, stream>>>(Hb, asb, adb, rowstart, csr, b2,
                                                 Xb, outf, 0, N, Etot);
    // layer 3 (K=256) -> fp32 d_out
    gemm_kernel<<<gemm_grid, 256, 0, stream>>>(Xb, Wt3, Hb, at_s3, at_d3, asb, adb, N, 256);
    gather_kernel<<<node_grid, 256, 0, stream>>>(Hb, asb, adb, rowstart, csr, b3,
                                                 Xb, outf, 1, N, Etot);
}

// Round 11
// 433.369 us; speedup vs baseline: 1.1483x; 1.0228x over previous
//
#include <hip/hip_runtime.h>
#include <hip/hip_bf16.h>
#include <stdint.h>

#define HEADS 4
#define SLOPE 0.2f

typedef unsigned short u16;
typedef float f32x4 __attribute__((ext_vector_type(4)));
typedef short s16x8 __attribute__((ext_vector_type(8)));
typedef unsigned short u16x4 __attribute__((ext_vector_type(4)));

__device__ __forceinline__ u16 f2bf(float f) {
    unsigned int u = __float_as_uint(f);
    u = (u + 0x7fffu + ((u >> 16) & 1u)) >> 16;   // round-to-nearest-even
    return (u16)u;
}
__device__ __forceinline__ float bf2f(u16 v) {
    return __uint_as_float(((unsigned int)v) << 16);
}
__device__ __forceinline__ float fin(float x) {
    return (x == x && fabsf(x) < 1e30f) ? x : 0.f;
}

// ---------------------------------------------------------------- fused prep + count
// Block-section mapping: [count atomics][cast inp->Xb][LDS-tiled W transposes].
// count is atomic-latency-bound (44us, VALU 2.5%); cast/transposes overlap it.
__global__ void prep_kernel(const float* __restrict__ inp, u16* __restrict__ Xb,
                            const float* __restrict__ W1, u16* __restrict__ Wt1,
                            const float* __restrict__ W2, u16* __restrict__ Wt2,
                            const float* __restrict__ W3, u16* __restrict__ Wt3,
                            const int* __restrict__ dst, int* __restrict__ deg,
                            int* __restrict__ rank, int E, int N) {
    __shared__ u16 tile[64][68];          // 68 pad: conflict-light column reads
    int Etot = E + N;
    int CB = (Etot + 255) >> 8;
    int XB = (N * 32 + 255) >> 8;
    int b = blockIdx.x;
    if (b < CB) {                          // --- count: rank-returning atomic
        int i = b * 256 + threadIdx.x;
        if (i < Etot) {
            int d = (i < E) ? dst[i] : (i - E);   // self-loops appended
            d = ((unsigned)d < (unsigned)N) ? d : 0;
            rank[i] = atomicAdd(&deg[d], 1);
        }
        return;
    }
    b -= CB;
    if (b < XB) {                          // --- cast inp -> Xb (vec4)
        int i = b * 256 + threadIdx.x;
        if (i < N * 32) {
            f32x4 v = *(const f32x4*)(inp + (size_t)i * 4);
            u16x4 o;
            #pragma unroll
            for (int j = 0; j < 4; j++) o[j] = f2bf(fin(v[j]));
            *(u16x4*)(Xb + (size_t)i * 4) = o;
        }
        return;
    }
    b -= XB;                               // --- transposes: 40 blocks of 64x64 tiles
    const float* W; u16* Wt; int K, kt, mt;
    if (b < 8)       { W = W1; Wt = Wt1; K = 128; kt = b >> 2; mt = b & 3; }
    else if (b < 24) { b -= 8;  W = W2; Wt = Wt2; K = 256; kt = b >> 2; mt = b & 3; }
    else             { b -= 24; W = W3; Wt = Wt3; K = 256; kt = b >> 2; mt = b & 3; }
    int k0 = kt * 64, m0 = mt * 64;
    int t = threadIdx.x;
    int rr = t >> 4, cc = (t & 15) * 4;
    #pragma unroll
    for (int j = 0; j < 4; j++) {
        int row = rr + 16 * j;                      // k-index
        f32x4 v = *(const f32x4*)(W + (size_t)(k0 + row) * 256 + m0 + cc);
        #pragma unroll
        for (int q = 0; q < 4; q++) tile[row][cc + q] = f2bf(fin(v[q]));
    }
    __syncthreads();
    #pragma unroll
    for (int j = 0; j < 4; j++) {
        int orow = rr + 16 * j;                     // m-index
        u16x4 o;
        #pragma unroll
        for (int q = 0; q < 4; q++) o[q] = tile[cc + q][orow];
        *(u16x4*)(Wt + (size_t)(m0 + orow) * K + k0 + cc) = o;   // coalesced
    }
}

// Single-dispatch scan: block b redundantly sums deg[0 .. b*1024), then scans
// its own 1024-element chunk (O(B^2) pre-sum is cheap at B=49).
__global__ __launch_bounds__(256) void scan_kernel(const int* __restrict__ deg,
                                                   int* __restrict__ rowstart, int N) {
    __shared__ int wsum[4];
    __shared__ int sm[256];
    int b = blockIdx.x, tid = threadIdx.x;
    int start = b * 1024;
    int pre = 0;
    for (int i = tid; i < start; i += 256) pre += deg[i];
    #pragma unroll
    for (int off = 1; off <= 32; off <<= 1) pre += __shfl_xor(pre, off);
    if ((tid & 63) == 0) wsum[tid >> 6] = pre;
    __syncthreads();
    int block_pre = wsum[0] + wsum[1] + wsum[2] + wsum[3];

    int base = start + tid * 4;
    int v[4]; int s = 0;
    #pragma unroll
    for (int j = 0; j < 4; j++) { int i = base + j; v[j] = (i < N) ? deg[i] : 0; s += v[j]; }
    sm[tid] = s;
    __syncthreads();
    for (int off = 1; off < 256; off <<= 1) {
        int t = (tid >= off) ? sm[tid - off] : 0;
        __syncthreads();
        sm[tid] += t;
        __syncthreads();
    }
    int run = block_pre + sm[tid] - s;
    #pragma unroll
    for (int j = 0; j < 4; j++) {
        int i = base + j;
        if (i < N) { rowstart[i] = run; run += v[j]; }
    }
    if (b == gridDim.x - 1 && tid == 255) rowstart[N] = block_pre + sm[255];
}

// ---------------------------------------------------------------- GEMM (+fused place)
// Blocks [0, mgrid): LDS-staged MFMA GEMM (64 x 256 tile, BK=64, 4 waves, one
// head per wave; LDS rows padded to 72 elems -> 2-way bank aliasing, free).
// Blocks [mgrid, ...): atomic-free CSR placement pos = rowstart[d] + rank[i].
// The two sections are independent (gemm needs Xb/Wt; place needs rowstart/rank)
// and complementary (gemm = MFMA/LDS-bound, place = scattered-store latency) ->
// place's ~40us hides under gemm1 instead of serializing after it.
__global__ __launch_bounds__(256, 3) void gemm_kernel(
        const u16* __restrict__ X, const u16* __restrict__ Wt,
        u16* __restrict__ Hout, const float* __restrict__ att_src,
        const float* __restrict__ att_dst, float* __restrict__ as_out,
        float* __restrict__ ad_out, int N, int K, int mgrid,
        const int* __restrict__ src, const int* __restrict__ dst,
        const int* __restrict__ rowstart, const int* __restrict__ rank,
        int* __restrict__ csr, int E) {
    if (blockIdx.x >= mgrid) {             // ---- place section
        int i = (blockIdx.x - mgrid) * 256 + threadIdx.x;
        if (i < E + N) {
            int s, d;
            if (i < E) { s = src[i]; d = dst[i]; }
            else       { s = i - E; d = i - E; }
            s = ((unsigned)s < (unsigned)N) ? s : 0;
            d = ((unsigned)d < (unsigned)N) ? d : 0;
            int pos = rowstart[d] + rank[i];
            if ((unsigned)pos < (unsigned)(E + N)) csr[pos] = s;
        }
        return;
    }
    __shared__ __align__(16) u16 As[64 * 72];    //  9216 B
    __shared__ __align__(16) u16 Bs[256 * 72];   // 36864 B
    int t = threadIdx.x;
    int wv = t >> 6, lane = t & 63;
    int quad = lane >> 4, l16 = lane & 15;
    int m0 = blockIdx.x * 64;
    int n0 = wv * 64;
    int srow = t >> 3, sslot = t & 7;   // staging: row-within-lot, 16B slot

    f32x4 acc[4][4];
    #pragma unroll
    for (int r = 0; r < 4; r++)
        #pragma unroll
        for (int c = 0; c < 4; c++) acc[r][c] = (f32x4){0.f, 0.f, 0.f, 0.f};

    const int nsteps = K >> 6;
    s16x8 ra[2], rb[8];
    {   // prologue: load k-step 0 to regs
        #pragma unroll
        for (int s = 0; s < 2; s++) {
            int rg = m0 + s * 32 + srow; rg = rg < N ? rg : N - 1;
            ra[s] = *(const s16x8*)(X + (size_t)rg * K + sslot * 8);
        }
        #pragma unroll
        for (int s = 0; s < 8; s++) {
            int n = s * 32 + srow;
            rb[s] = *(const s16x8*)(Wt + (size_t)n * K + sslot * 8);
        }
    }
    for (int step = 0; step < nsteps; step++) {
        __syncthreads();
        #pragma unroll
        for (int s = 0; s < 2; s++)
            *(s16x8*)(As + (s * 32 + srow) * 72 + sslot * 8) = ra[s];
        #pragma unroll
        for (int s = 0; s < 8; s++)
            *(s16x8*)(Bs + (s * 32 + srow) * 72 + sslot * 8) = rb[s];
        __syncthreads();
        if (step + 1 < nsteps) {        // prefetch next k-step (overlaps MFMA)
            int k0 = (step + 1) << 6;
            #pragma unroll
            for (int s = 0; s < 2; s++) {
                int rg = m0 + s * 32 + srow; rg = rg < N ? rg : N - 1;
                ra[s] = *(const s16x8*)(X + (size_t)rg * K + k0 + sslot * 8);
            }
            #pragma unroll
            for (int s = 0; s < 8; s++) {
                int n = s * 32 + srow;
                rb[s] = *(const s16x8*)(Wt + (size_t)n * K + k0 + sslot * 8);
            }
        }
        #pragma unroll
        for (int subk = 0; subk < 2; subk++) {
            s16x8 af[4], bfr[4];
            #pragma unroll
            for (int r = 0; r < 4; r++)
                af[r] = *(const s16x8*)(As + (r * 16 + l16) * 72 + subk * 32 + quad * 8);
            #pragma unroll
            for (int c = 0; c < 4; c++)
                bfr[c] = *(const s16x8*)(Bs + (n0 + c * 16 + l16) * 72 + subk * 32 + quad * 8);
            #pragma unroll
            for (int r = 0; r < 4; r++)
                #pragma unroll
                for (int c = 0; c < 4; c++)
                    acc[r][c] = __builtin_amdgcn_mfma_f32_16x16x32_bf16(af[r], bfr[c], acc[r][c], 0, 0, 0);
        }
    }

    // Epilogue: store bf16 H and alpha partials. C/D layout:
    // col = n0 + c*16 + l16, row = m0 + r*16 + quad*4 + j. Wave = head wv.
    float aps[4][4], apd[4][4];   // [r][j]
    #pragma unroll
    for (int r = 0; r < 4; r++)
        #pragma unroll
        for (int j = 0; j < 4; j++) { aps[r][j] = 0.f; apd[r][j] = 0.f; }

    #pragma unroll
    for (int r = 0; r < 4; r++) {
        int rowb = m0 + r * 16 + quad * 4;
        #pragma unroll
        for (int c = 0; c < 4; c++) {
            int col = n0 + c * 16 + l16;
            float av = fin(att_src[col]);
            float dv = fin(att_dst[col]);
            #pragma unroll
            for (int j = 0; j < 4; j++) {
                int row = rowb + j;
                float v = acc[r][c][j];
                aps[r][j] += v * av;
                apd[r][j] += v * dv;
                if (row < N) Hout[(size_t)row * 256 + col] = f2bf(v);
            }
        }
    }
    #pragma unroll
    for (int off = 1; off <= 8; off <<= 1)
        #pragma unroll
        for (int r = 0; r < 4; r++)
            #pragma unroll
            for (int j = 0; j < 4; j++) {
                aps[r][j] += __shfl_xor(aps[r][j], off);
                apd[r][j] += __shfl_xor(apd[r][j], off);
            }
    if (l16 == 0) {
        #pragma unroll
        for (int r = 0; r < 4; r++) {
            int rowb = m0 + r * 16 + quad * 4;
            #pragma unroll
            for (int j = 0; j < 4; j++) {
                int row = rowb + j;
                if (row < N) {
                    as_out[row * 4 + wv] = aps[r][j];
                    ad_out[row * 4 + wv] = apd[r][j];
                }
            }
        }
    }
}

// ---------------------------------------------------------------- fused softmax-gather
// Wave per node; 2 half-wave edge slots; lane covers 8 channels (16 B load) of
// head h = (lane&31)>>3. Inline max-free softmax (clamp 80). Edge loop unrolled
// x4 per slot -> 8 independent row loads in flight per wave.
__global__ __launch_bounds__(256) void gather_kernel(
        const u16* __restrict__ Hb, const float* __restrict__ asrc,
        const float* __restrict__ adst, const int* __restrict__ rowstart,
        const int* __restrict__ csr, const float* __restrict__ bias,
        u16* __restrict__ outb, float* __restrict__ outf, int write_f32,
        int N, int Etot) {
    int wv = threadIdx.x >> 6, lane = threadIdx.x & 63;
    int n = blockIdx.x * 4 + wv;
    if (n >= N) return;
    int es = lane >> 5, c = lane & 31;    // edge slot; 8-channel group
    int h = c >> 3;
    int i0 = rowstart[n], i1 = rowstart[n + 1];
    i0 = min(max(i0, 0), Etot);
    i1 = min(max(i1, i0), Etot);

    float adh = adst[n * 4 + h];
    float acc[8];
    float ws = 0.f;
    #pragma unroll
    for (int j = 0; j < 8; j++) acc[j] = 0.f;

    int i = i0 + es;
    for (; i + 6 < i1; i += 8) {          // x4 unroll: 4 independent lines/slot
        int ss[4];
        #pragma unroll
        for (int u = 0; u < 4; u++) {
            int s = csr[i + 2 * u];
            ss[u] = ((unsigned)s < (unsigned)N) ? s : 0;
        }
        float e[4]; s16x8 hv[4];
        #pragma unroll
        for (int u = 0; u < 4; u++) {
            e[u] = asrc[ss[u] * 4 + h] + adh;
            hv[u] = *(const s16x8*)(Hb + (size_t)ss[u] * 256 + c * 8);
        }
        #pragma unroll
        for (int u = 0; u < 4; u++) {
            float ee = e[u] > 0.f ? e[u] : SLOPE * e[u];
            float w = __expf(fminf(ee, 80.f));
            ws += w;
            #pragma unroll
            for (int j = 0; j < 8; j++) acc[j] += w * bf2f((u16)hv[u][j]);
        }
    }
    for (; i + 2 < i1; i += 4) {
        int sA = csr[i], sB = csr[i + 2];
        sA = ((unsigned)sA < (unsigned)N) ? sA : 0;
        sB = ((unsigned)sB < (unsigned)N) ? sB : 0;
        float eA = asrc[sA * 4 + h] + adh;
        float eB = asrc[sB * 4 + h] + adh;
        s16x8 hvA = *(const s16x8*)(Hb + (size_t)sA * 256 + c * 8);
        s16x8 hvB = *(const s16x8*)(Hb + (size_t)sB * 256 + c * 8);
        eA = eA > 0.f ? eA : SLOPE * eA;
        eB = eB > 0.f ? eB : SLOPE * eB;
        float wA = __expf(fminf(eA, 80.f));
        float wB = __expf(fminf(eB, 80.f));
        ws += wA + wB;
        #pragma unroll
        for (int j = 0; j < 8; j++)
            acc[j] += wA * bf2f((u16)hvA[j]) + wB * bf2f((u16)hvB[j]);
    }
    if (i < i1) {
        int s = csr[i];
        s = ((unsigned)s < (unsigned)N) ? s : 0;
        float e = asrc[s * 4 + h] + adh;
        s16x8 hv = *(const s16x8*)(Hb + (size_t)s * 256 + c * 8);
        e = e > 0.f ? e : SLOPE * e;
        float w = __expf(fminf(e, 80.f));
        ws += w;
        #pragma unroll
        for (int j = 0; j < 8; j++) acc[j] += w * bf2f((u16)hv[j]);
    }

    ws += __shfl_xor(ws, 32);
    #pragma unroll
    for (int j = 0; j < 8; j++) acc[j] += __shfl_xor(acc[j], 32);

    if (es == 0) {
        float invh = (ws > 0.f) ? 1.f / ws : 0.f;
        f32x4 blo = *(const f32x4*)(bias + c * 8);
        f32x4 bhi = *(const f32x4*)(bias + c * 8 + 4);
        size_t base = (size_t)n * 256 + c * 8;
        float o[8];
        #pragma unroll
        for (int j = 0; j < 8; j++) {
            float v = acc[j] * invh + fin(j < 4 ? blo[j] : bhi[j - 4]);
            o[j] = v > 0.f ? v : (__expf(v) - 1.f);   // ELU
        }
        if (write_f32) {
            f32x4 lo = {o[0], o[1], o[2], o[3]}, hi = {o[4], o[5], o[6], o[7]};
            *(f32x4*)(outf + base) = lo;
            *(f32x4*)(outf + base + 4) = hi;
        } else {
            s16x8 ob;
            #pragma unroll
            for (int j = 0; j < 8; j++) ob[j] = (short)f2bf(o[j]);
            *(s16x8*)(outb + base) = ob;
        }
    }
}

// ---------------------------------------------------------------- launch
extern "C" void kernel_launch(void* const* d_in, const int* in_sizes, int n_in,
                              void* d_out, int out_size, void* d_ws, size_t ws_size,
                              hipStream_t stream) {
    const float* inp  = (const float*)d_in[0];
    const int*   ei   = (const int*)d_in[1];
    const float* W1   = (const float*)d_in[2];
    const float* at_s1= (const float*)d_in[3];
    const float* at_d1= (const float*)d_in[4];
    const float* b1   = (const float*)d_in[5];
    const float* W2   = (const float*)d_in[6];
    const float* at_s2= (const float*)d_in[7];
    const float* at_d2= (const float*)d_in[8];
    const float* b2   = (const float*)d_in[9];
    const float* W3   = (const float*)d_in[10];
    const float* at_s3= (const float*)d_in[11];
    const float* at_d3= (const float*)d_in[12];
    const float* b3   = (const float*)d_in[13];

    const int N = in_sizes[0] / 128;   // 50000
    const int E = in_sizes[1] / 2;     // 800000
    const int Etot = E + N;
    const int* esrc = ei;
    const int* edst = ei + E;

    char* p = (char*)d_ws;
    auto alloc = [&](size_t b) -> void* {
        void* q = (void*)p;
        p += (b + 255) & ~(size_t)255;
        return q;
    };
    u16*   Xb       = (u16*)alloc((size_t)N * 256 * 2);
    u16*   Hb       = (u16*)alloc((size_t)N * 256 * 2);
    u16*   Wt1      = (u16*)alloc((size_t)128 * 256 * 2);
    u16*   Wt2      = (u16*)alloc((size_t)256 * 256 * 2);
    u16*   Wt3      = (u16*)alloc((size_t)256 * 256 * 2);
    float* asb      = (float*)alloc((size_t)N * 4 * 4);
    float* adb      = (float*)alloc((size_t)N * 4 * 4);
    int*   deg      = (int*)alloc((size_t)N * 4);
    int*   rowstart = (int*)alloc((size_t)(N + 1) * 4);
    int*   rank     = (int*)alloc((size_t)Etot * 4);
    int*   csr      = (int*)alloc((size_t)Etot * 4);
    float* outf     = (float*)d_out;

    const int SB = (N + 1023) / 1024;
    const int CB = (Etot + 255) >> 8;
    const int XB = (N * 32 + 255) >> 8;
    const int prep_blocks = CB + XB + 40;

    hipMemsetAsync(deg, 0, (size_t)N * 4, stream);
    prep_kernel<<<prep_blocks, 256, 0, stream>>>(
        inp, Xb, W1, Wt1, W2, Wt2, W3, Wt3, edst, deg, rank, E, N);
    scan_kernel<<<SB, 256, 0, stream>>>(deg, rowstart, N);

    const int gemm_grid  = (N + 63) / 64;
    const int place_grid = (Etot + 255) / 256;
    const int node_grid  = (N + 3) / 4;

    // layer 1 (K=128), with place fused as extra blocks (independent sections)
    gemm_kernel<<<gemm_grid + place_grid, 256, 0, stream>>>(
        Xb, Wt1, Hb, at_s1, at_d1, asb, adb, N, 128, gemm_grid,
        esrc, edst, rowstart, rank, csr, E);
    gather_kernel<<<node_grid, 256, 0, stream>>>(Hb, asb, adb, rowstart, csr, b1,
                                                 Xb, outf, 0, N, Etot);
    // layer 2 (K=256)
    gemm_kernel<<<gemm_grid, 256, 0, stream>>>(
        Xb, Wt2, Hb, at_s2, at_d2, asb, adb, N, 256, gemm_grid,
        esrc, edst, rowstart, rank, csr, E);
    gather_kernel<<<node_grid, 256, 0, stream>>>(Hb, asb, adb, rowstart, csr, b2,
                                                 Xb, outf, 0, N, Etot);
    // layer 3 (K=256) -> fp32 d_out
    gemm_kernel<<<gemm_grid, 256, 0, stream>>>(
        Xb, Wt3, Hb, at_s3, at_d3, asb, adb, N, 256, gemm_grid,
        esrc, edst, rowstart, rank, csr, E);
    gather_kernel<<<node_grid, 256, 0, stream>>>(Hb, asb, adb, rowstart, csr, b3,
                                                 Xb, outf, 1, N, Etot);
}